// Round 5
// baseline (416.847 us; speedup 1.0000x reference)
//
#include <hip/hip_runtime.h>
#include <math.h>

#define TT 2048
#define HH 1024
#define NE 40
#define ER 32
#define II 512
#define TOPK 4
#define RSCALE 2.5f
#define MAXW 64    // max m-tiles of 256: 8192/256 + 32

typedef __bf16 bf16x8 __attribute__((ext_vector_type(8)));
typedef float f32x4 __attribute__((ext_vector_type(4)));

// async global->LDS, 16B per lane; LDS dest is wave-uniform base + lane*16
__device__ __forceinline__ void glds16(const void* g, void* l) {
  __builtin_amdgcn_global_load_lds(
      (const __attribute__((address_space(1))) unsigned int*)g,
      (__attribute__((address_space(3))) unsigned int*)l, 16, 0, 0);
}

__device__ __forceinline__ void st_bf8(void* dst, float4 lo, float4 hi) {
  union { __bf16 h[8]; uint4 u; } pk;
  pk.h[0] = (__bf16)lo.x; pk.h[1] = (__bf16)lo.y;
  pk.h[2] = (__bf16)lo.z; pk.h[3] = (__bf16)lo.w;
  pk.h[4] = (__bf16)hi.x; pk.h[5] = (__bf16)hi.y;
  pk.h[6] = (__bf16)hi.z; pk.h[7] = (__bf16)hi.w;
  *(uint4*)dst = pk.u;
}

// ---------------- K0: zero the global expert counters -----------------------
__global__ __launch_bounds__(64) void k_zero(int* __restrict__ cnt) {
  if (threadIdx.x < 32) cnt[threadIdx.x] = 0;
}

// ---------------- K1: fused router (batched-butterfly, latency-fixed) -------
__global__ __launch_bounds__(256) void k_router(const float* __restrict__ hidden,
                                                const float* __restrict__ rw,
                                                const float* __restrict__ bias,
                                                float* __restrict__ out,
                                                int* __restrict__ tok4_id,
                                                float* __restrict__ tok4_w,
                                                __bf16* __restrict__ hid_bf,
                                                int* __restrict__ cnt) {
  int lane = threadIdx.x & 63;
  int t = blockIdx.x * 4 + (threadIdx.x >> 6);
  const float* hrow = hidden + (size_t)t * HH;
  float4 hv[4];
  #pragma unroll
  for (int c = 0; c < 4; c++) hv[c] = *(const float4*)(hrow + c * 256 + lane * 4);

  float acc[NE];
  #pragma unroll
  for (int e = 0; e < NE; e++) {
    const float* wrow = rw + (size_t)e * HH;
    float p = 0.f;
    #pragma unroll
    for (int c = 0; c < 4; c++) {
      float4 w4 = *(const float4*)(wrow + c * 256 + lane * 4);
      p += hv[c].x * w4.x + hv[c].y * w4.y + hv[c].z * w4.z + hv[c].w * w4.w;
    }
    acc[e] = p;
  }
  // batched butterfly: 6 rounds x 40 independent adds, fully pipelined
  #pragma unroll
  for (int off = 32; off; off >>= 1)
    #pragma unroll
    for (int e = 0; e < NE; e++) acc[e] += __shfl_xor(acc[e], off);

  // every lane holds all 40 logits -> per-lane uniform softmax/top-4
  float m = acc[0];
  #pragma unroll
  for (int e = 1; e < NE; e++) m = fmaxf(m, acc[e]);
  float s = 0.f;
  #pragma unroll
  for (int e = 0; e < NE; e++) { acc[e] = expf(acc[e] - m); s += acc[e]; }
  float inv = 1.f / s;
  float v[NE];
  #pragma unroll
  for (int e = 0; e < NE; e++) { acc[e] *= inv; v[e] = acc[e] + bias[e]; }

  int ids[TOPK]; float wv[TOPK];
  #pragma unroll
  for (int k = 0; k < TOPK; k++) {
    float mv = -INFINITY, mw = 0.f; int mi = 0;
    #pragma unroll
    for (int e = 0; e < NE; e++)
      if (v[e] > mv) { mv = v[e]; mi = e; mw = acc[e]; }   // strict > : tie -> lower idx
    ids[k] = mi;
    wv[k] = RSCALE * mw;                                   // weight from UNBIASED score
    #pragma unroll
    for (int e = 0; e < NE; e++) if (e == mi) v[e] = -INFINITY;  // static idx
  }
  float zt = 0.f;
  #pragma unroll
  for (int k = 0; k < TOPK; k++) if (ids[k] >= ER) zt += wv[k];
  if (lane == 0) {
    #pragma unroll
    for (int k = 0; k < TOPK; k++) {
      tok4_id[t * TOPK + k] = ids[k];
      tok4_w[t * TOPK + k] = wv[k];
      if (ids[k] < ER) atomicAdd(&cnt[ids[k]], 1);
    }
  }
  #pragma unroll
  for (int c = 0; c < 4; c++) {
    int j = c * 256 + lane * 4;
    float4 h4 = hv[c];
    *(float4*)(out + (size_t)t * HH + j) =
        make_float4(h4.x * zt, h4.y * zt, h4.z * zt, h4.w * zt);
    union { __bf16 h[4]; uint2 u; } pk;
    pk.h[0] = (__bf16)h4.x; pk.h[1] = (__bf16)h4.y;
    pk.h[2] = (__bf16)h4.z; pk.h[3] = (__bf16)h4.w;
    *(uint2*)(hid_bf + (size_t)t * HH + j) = pk.u;
  }
}

// ---------------- K2a: tiny scan over 32 counters + worklist ----------------
__global__ __launch_bounds__(64) void k_scan(const int* __restrict__ cnt,
                                             int* __restrict__ offs,
                                             int* __restrict__ wl_e,
                                             int* __restrict__ wl_m0,
                                             int* __restrict__ nwork,
                                             int* __restrict__ gcur) {
  int lane = threadIdx.x;
  int c = (lane < ER) ? cnt[lane] : 0;
  int ts = (c + 255) >> 8;                  // 256-row tiles
  int ps = c, pt = ts;
  #pragma unroll
  for (int off = 1; off < 32; off <<= 1) {
    int v1 = __shfl_up(ps, off);
    int v2 = __shfl_up(pt, off);
    if (lane >= off) { ps += v1; pt += v2; }
  }
  if (lane < ER) {
    int o = ps - c;
    offs[lane] = o; gcur[lane] = o;
    int tb = pt - ts;
    for (int i = 0; i < ts; i++) { wl_e[tb + i] = lane; wl_m0[tb + i] = i * 256; }
  }
  if (lane == 31) *nwork = pt;
}

// ---------------- K2b: parallel scatter (32 blocks, global-atomic slots) ----
__global__ __launch_bounds__(256) void k_scatter(const int* __restrict__ tok4_id,
                                                 const float* __restrict__ tok4_w,
                                                 int* __restrict__ gcur,
                                                 int* __restrict__ pair_tok,
                                                 float* __restrict__ pair_w) {
  int idx = blockIdx.x * 256 + threadIdx.x;
  int id = tok4_id[idx];
  if (id < ER) {
    int pos = atomicAdd(&gcur[id], 1);
    pair_tok[pos] = idx >> 2;
    pair_w[pos] = tok4_w[idx];
  }
}

// ---------------- K3: h = silu(X@Wg^T)*(X@Wu^T), M=256 x 32 cols, BK=32 -----
// OCCUPANCY round: all prior inner-loop variants sat at 83-88us at 1 block/CU
// (LDS 73-84KB). BK 64->32 shrinks LDS to 40KB -> 4 blocks/CU; the simple
// m97-style loop (glds A + reg-staged B + one __syncthreads) relies on
// inter-block TLP to hide the per-iter drain (m97/m114 mechanism). Weight
// traffic (the HBM term) is unchanged by BK.
// Swizzle for 64B rows: phys_chunk = chunk ^ (r&3) ^ ((r>>2)&3); applied on
// the global SOURCE for glds-A (dest linear), on ds_write addr for B, and on
// the read side; balanced 8-hits/bank per wave access.
__global__ __launch_bounds__(256, 4) void k_w13(const __bf16* __restrict__ hid_bf,
                                                const float* __restrict__ w13,
                                                const int* __restrict__ cnt,
                                                const int* __restrict__ offs,
                                                const int* __restrict__ pair_tok,
                                                const int* __restrict__ wl_e,
                                                const int* __restrict__ wl_m0,
                                                const int* __restrict__ nwork,
                                                __bf16* __restrict__ h_buf) {
  int bx = blockIdx.x;
  if (bx >= *nwork) return;
  int e = wl_e[bx], m0w = wl_m0[bx];
  int M = cnt[e] - m0w; if (M > 256) M = 256;
  int base = offs[e] + m0w;
  int n0 = blockIdx.y * 32;

  __shared__ __bf16 As[2][256][32];   // 32KB
  __shared__ __bf16 Bs[2][64][32];    // 8KB: rows 0-31 gate, 32-63 up

  int tid = threadIdx.x;
  int lane = tid & 63, w = tid >> 6;
  int quad = lane >> 4, rr = lane & 15;
  int lr = lane >> 2, lc = lane & 3;            // A-stage: row-in-16, chunk
  int swzs = (lr & 3) ^ ((lr >> 2) & 3);        // stage-side swizzle (row&7 bits via lr)
  int swzr = (rr & 3) ^ ((rr >> 2) & 3);        // read-side swizzle
  int cx = ((quad ^ swzr) & 3) * 16;            // phys chunk byte offset for reads

  // A glds sources: p in 0..3, row = p*64 + w*16 + lr; source chunk lc^swz
  const __bf16* asrc[4];
  #pragma unroll
  for (int p = 0; p < 4; p++) {
    int row = p * 64 + w * 16 + lr;
    int tok = pair_tok[base + ((row < M) ? row : 0)];
    asrc[p] = hid_bf + (size_t)tok * HH + (lc ^ swzs) * 8;
  }
  // B: thread stages phys chunk (brow, lc); fetches logical chunk lc^swz(brow)
  int brow = tid >> 2;
  int bswz = (brow & 3) ^ ((brow >> 2) & 3);
  int wrow = (brow < 32) ? (n0 + brow) : (II + n0 + brow - 32);
  const float* bsrc = w13 + (size_t)e * (2 * II) * HH + (size_t)wrow * HH +
                      ((lc ^ bswz) * 8);
  int bdoff = brow * 64 + lc * 16;              // byte offset in Bs[buf]

  f32x4 accg[4][2] = {};
  f32x4 accu[4][2] = {};

  // prologue: stage t=0
  #pragma unroll
  for (int p = 0; p < 4; p++) glds16(asrc[p], &As[0][p * 64 + w * 16][0]);
  st_bf8((char*)&Bs[0][0][0] + bdoff, *(const float4*)bsrc, *(const float4*)(bsrc + 4));
  __syncthreads();

  const int NT = HH / 32;
  int cur = 0;
  for (int t = 0; t < NT; t++) {
    bool pf = (t + 1 < NT);
    float4 lo, hi;
    if (pf) {                                   // issue t+1 stage (overlaps MFMA issue)
      int kk = (t + 1) * 32;
      #pragma unroll
      for (int p = 0; p < 4; p++) glds16(asrc[p] + kk, &As[cur ^ 1][p * 64 + w * 16][0]);
      lo = *(const float4*)(bsrc + kk);
      hi = *(const float4*)(bsrc + kk + 4);
    }
    const char* ac = (const char*)&As[cur][0][0];
    const char* bc = (const char*)&Bs[cur][0][0];
    bf16x8 av[4], bg[2], bu[2];
    #pragma unroll
    for (int i = 0; i < 4; i++)
      av[i] = *(const bf16x8*)(ac + (w * 64 + i * 16 + rr) * 64 + cx);
    #pragma unroll
    for (int j = 0; j < 2; j++) {
      bg[j] = *(const bf16x8*)(bc + (j * 16 + rr) * 64 + cx);
      bu[j] = *(const bf16x8*)(bc + (32 + j * 16 + rr) * 64 + cx);
    }
    #pragma unroll
    for (int i = 0; i < 4; i++)
      #pragma unroll
      for (int j = 0; j < 2; j++) {
        accg[i][j] = __builtin_amdgcn_mfma_f32_16x16x32_bf16(av[i], bg[j], accg[i][j], 0, 0, 0);
        accu[i][j] = __builtin_amdgcn_mfma_f32_16x16x32_bf16(av[i], bu[j], accu[i][j], 0, 0, 0);
      }
    if (pf) st_bf8((char*)&Bs[cur ^ 1][0][0] + bdoff, lo, hi);
    __syncthreads();
    cur ^= 1;
  }

  #pragma unroll
  for (int i = 0; i < 4; i++)
    #pragma unroll
    for (int j = 0; j < 2; j++)
      #pragma unroll
      for (int l = 0; l < 4; l++) {
        int m = w * 64 + i * 16 + quad * 4 + l;
        if (m < M) {
          float g = accg[i][j][l], u = accu[i][j][l];
          float hv = g / (1.f + expf(-g)) * u;
          h_buf[(size_t)(base + m) * II + n0 + j * 16 + rr] = (__bf16)hv;
        }
      }
}

// ---------------- K4: out[t] += w_p * (h @ w2[e]^T), M=256 x N=64, BK=32 ----
// Same 40KB occupancy structure; A rows contiguous in h_buf.
__global__ __launch_bounds__(256, 4) void k_w2(const __bf16* __restrict__ h_buf,
                                               const float* __restrict__ w2,
                                               const int* __restrict__ cnt,
                                               const int* __restrict__ offs,
                                               const int* __restrict__ pair_tok,
                                               const float* __restrict__ pair_w,
                                               const int* __restrict__ wl_e,
                                               const int* __restrict__ wl_m0,
                                               const int* __restrict__ nwork,
                                               float* __restrict__ out) {
  int bx = blockIdx.x;
  if (bx >= *nwork) return;
  int e = wl_e[bx], m0w = wl_m0[bx];
  int M = cnt[e] - m0w; if (M > 256) M = 256;
  int base = offs[e] + m0w;
  int h0 = blockIdx.y * 64;

  __shared__ __bf16 As[2][256][32];   // 32KB
  __shared__ __bf16 Bs[2][64][32];    // 8KB
  __shared__ int tl[256];
  __shared__ float wl[256];

  int tid = threadIdx.x;
  int lane = tid & 63, w = tid >> 6;
  int quad = lane >> 4, rr = lane & 15;
  int lr = lane >> 2, lc = lane & 3;
  int swzs = (lr & 3) ^ ((lr >> 2) & 3);
  int swzr = (rr & 3) ^ ((rr >> 2) & 3);
  int cx = ((quad ^ swzr) & 3) * 16;

  {
    int ok = tid < M;
    tl[tid] = ok ? pair_tok[base + tid] : 0;
    wl[tid] = ok ? pair_w[base + tid] : 0.f;
  }

  // A: contiguous h_buf rows (rows >= M read in-bounds junk, masked at write)
  const __bf16* asrc[4];
  #pragma unroll
  for (int p = 0; p < 4; p++) {
    int row = p * 64 + w * 16 + lr;
    asrc[p] = h_buf + (size_t)(base + row) * II + (lc ^ swzs) * 8;
  }
  // B: w2 rows h0..h0+63
  int brow = tid >> 2;
  int bswz = (brow & 3) ^ ((brow >> 2) & 3);
  const float* bsrc = w2 + (size_t)e * HH * II + (size_t)(h0 + brow) * II +
                      ((lc ^ bswz) * 8);
  int bdoff = brow * 64 + lc * 16;

  f32x4 acc[4][4] = {};

  #pragma unroll
  for (int p = 0; p < 4; p++) glds16(asrc[p], &As[0][p * 64 + w * 16][0]);
  st_bf8((char*)&Bs[0][0][0] + bdoff, *(const float4*)bsrc, *(const float4*)(bsrc + 4));
  __syncthreads();

  const int NT = II / 32;
  int cur = 0;
  for (int t = 0; t < NT; t++) {
    bool pf = (t + 1 < NT);
    float4 lo, hi;
    if (pf) {
      int kk = (t + 1) * 32;
      #pragma unroll
      for (int p = 0; p < 4; p++) glds16(asrc[p] + kk, &As[cur ^ 1][p * 64 + w * 16][0]);
      lo = *(const float4*)(bsrc + kk);
      hi = *(const float4*)(bsrc + kk + 4);
    }
    const char* ac = (const char*)&As[cur][0][0];
    const char* bc = (const char*)&Bs[cur][0][0];
    bf16x8 av[4], b[4];
    #pragma unroll
    for (int i = 0; i < 4; i++)
      av[i] = *(const bf16x8*)(ac + (w * 64 + i * 16 + rr) * 64 + cx);
    #pragma unroll
    for (int j = 0; j < 4; j++)
      b[j] = *(const bf16x8*)(bc + (j * 16 + rr) * 64 + cx);
    #pragma unroll
    for (int i = 0; i < 4; i++)
      #pragma unroll
      for (int j = 0; j < 4; j++)
        acc[i][j] = __builtin_amdgcn_mfma_f32_16x16x32_bf16(av[i], b[j], acc[i][j], 0, 0, 0);
    if (pf) st_bf8((char*)&Bs[cur ^ 1][0][0] + bdoff, lo, hi);
    __syncthreads();
    cur ^= 1;
  }

  #pragma unroll
  for (int i = 0; i < 4; i++)
    #pragma unroll
    for (int l = 0; l < 4; l++) {
      int m = w * 64 + i * 16 + quad * 4 + l;
      if (m < M) {
        int t = tl[m];
        float wp = wl[m];
        #pragma unroll
        for (int j = 0; j < 4; j++)
          atomicAdd(&out[(size_t)t * HH + h0 + j * 16 + rr], acc[i][j][l] * wp);
      }
    }
}

extern "C" void kernel_launch(void* const* d_in, const int* in_sizes, int n_in,
                              void* d_out, int out_size, void* d_ws, size_t ws_size,
                              hipStream_t stream) {
  const float* hidden = (const float*)d_in[0];
  const float* rw     = (const float*)d_in[1];
  const float* bias   = (const float*)d_in[2];
  const float* w13    = (const float*)d_in[3];
  const float* w2     = (const float*)d_in[4];
  float* out = (float*)d_out;

  int* ws_i = (int*)d_ws;
  int* tok4_id = ws_i;                                    // TT*4
  float* tok4_w = (float*)(tok4_id + TT * TOPK);          // TT*4
  int* pair_tok = (int*)(tok4_w + TT * TOPK);             // TT*4
  float* pair_w = (float*)(pair_tok + TT * TOPK);         // TT*4
  int* cnt = (int*)(pair_w + TT * TOPK);                  // 32
  int* offs = cnt + 32;                                   // 32
  int* wl_e = offs + 32;                                  // 64
  int* wl_m0 = wl_e + 64;                                 // 64
  int* nwork = wl_m0 + 64;                                // 64-int region
  int* gcur = nwork + 16;                                 // 32 (inside region)
  __bf16* hid_bf = (__bf16*)(nwork + 64);                 // TT*HH
  __bf16* h_buf = hid_bf + (size_t)TT * HH;               // (TT*4+256)*II

  k_zero<<<dim3(1), dim3(64), 0, stream>>>(cnt);
  k_router<<<dim3(TT / 4), dim3(256), 0, stream>>>(hidden, rw, bias, out,
                                                   tok4_id, tok4_w, hid_bf, cnt);
  k_scan<<<dim3(1), dim3(64), 0, stream>>>(cnt, offs, wl_e, wl_m0, nwork, gcur);
  k_scatter<<<dim3(32), dim3(256), 0, stream>>>(tok4_id, tok4_w, gcur, pair_tok, pair_w);
  k_w13<<<dim3(MAXW, 16), dim3(256), 0, stream>>>(hid_bf, w13, cnt, offs, pair_tok,
                                                  wl_e, wl_m0, nwork, h_buf);
  k_w2<<<dim3(MAXW, 16), dim3(256), 0, stream>>>(h_buf, w2, cnt, offs, pair_tok, pair_w,
                                                 wl_e, wl_m0, nwork, out);
}